// Round 3
// baseline (1487.014 us; speedup 1.0000x reference)
//
#include <hip/hip_runtime.h>
#include <math.h>

typedef _Float16 half_t;
typedef half_t half8 __attribute__((ext_vector_type(8)));
typedef half_t half4 __attribute__((ext_vector_type(4)));
typedef float  f32x4 __attribute__((ext_vector_type(4)));
typedef double dbl2  __attribute__((ext_vector_type(2)));

// Problem constants
#define BB 4
#define HH 512
#define WW 512
#define IMGPIX (HH*WW)        // 262144
#define KSEL 512
#define NPROP (BB*KSEL)       // 2048
#define CUP 64
#define NMS_THR 0.2f

// Workspace layout (bytes)
#define OFF_S32    0                      // double[4096] = 32768
#define OFF_SUM    32768                  // double
#define OFF_CNT    32776                  // ull
#define OFF_CCNT   32784                  // u32[4]
#define OFF_HIST   32800                  // u32[4][4][4096] = 262144
#define ZERO_BASE  32768
#define ZERO_LEN   262176                 // sum..hist inclusive
#define OFF_PFX    294944                 // ull[4]
#define OFF_R      294976                 // u32[4]
#define OFF_BITMAP 295040                 // u64[16384] = 131072
#define OFF_BM     426112                 // float[1048576] = 4 MB
#define OFF_RM     4620416                // 4 MB
#define OFF_KEYS   8814720                // u64[1048576] = 8 MB
#define OFF_SEL    17203328               // u64[2048] = 16384
#define OFF_PROPS  17219712               // int[4096] = 16384
#define OFF_W1     17236096               // 294912
#define OFF_W2     17531008               // 1179648
#define OFF_W3     18710656               // 1179648 -> 19890304 total

#define LRELU_F(x) ((x) > 0.0f ? (x) : 0.1f*(x))

// ---------------------------------------------------------------------------
// Stage 1: per-pixel patch MLP (f64), 8 px per block, 512 blocks
// ---------------------------------------------------------------------------
__global__ __launch_bounds__(256) void patch_k(
    const float* __restrict__ fdown,
    const float* __restrict__ pw1, const float* __restrict__ pb1,
    const float* __restrict__ pw2, const float* __restrict__ pb2,
    const float* __restrict__ pw3, const float* __restrict__ pb3,
    const float* __restrict__ pfcw, const float* __restrict__ pfcb,
    double* __restrict__ s32)
{
  __shared__ __align__(16) double xb[8][256];
  const int t = threadIdx.x;
  const int base_px = blockIdx.x * 8;
#pragma unroll
  for (int p = 0; p < 8; ++p) {
    int px = base_px + p;
    int b = px >> 10, rem = px & 1023;
    xb[p][t] = (double)fdown[(size_t)(b*256 + t)*1024 + rem];
  }
  __syncthreads();
  const float* Ws[3] = {pw1, pw2, pw3};
  const float* Bs[3] = {pb1, pb2, pb3};
  for (int L = 0; L < 3; ++L) {
    double acc[8];
    double bias = (double)Bs[L][t];
#pragma unroll
    for (int p = 0; p < 8; ++p) acc[p] = bias;
    const float* wrow = Ws[L] + t*256;
    for (int c = 0; c < 256; c += 2) {
      double w0 = (double)wrow[c], w1 = (double)wrow[c+1];
#pragma unroll
      for (int p = 0; p < 8; ++p) {
        dbl2 xv = *(const dbl2*)&xb[p][c];
        acc[p] += w0 * xv.x;
        acc[p] += w1 * xv.y;
      }
    }
    __syncthreads();
#pragma unroll
    for (int p = 0; p < 8; ++p)
      xb[p][t] = acc[p] > 0.0 ? acc[p] : 0.1*acc[p];
    __syncthreads();
  }
  if (t < 8) {
    double l0 = (double)pfcb[0], l1 = (double)pfcb[1];
    for (int c = 0; c < 256; ++c) {
      double xv = xb[t][c];
      l0 += (double)pfcw[c]       * xv;
      l1 += (double)pfcw[256 + c] * xv;
    }
    double m  = fmax(l0, l1);
    double e0 = exp(l0 - m), e1 = exp(l1 - m);
    s32[base_px + t] = e1 / (e0 + e1);
  }
}

// Bilinear upsample 32->512 (align_corners=False), matches jax.image.resize.
__device__ __forceinline__ double upsample_ps(const double* __restrict__ s32,
                                              int b, int oy, int ox)
{
  double sy = (oy + 0.5)*0.0625 - 0.5;
  double sx = (ox + 0.5)*0.0625 - 0.5;
  double fy = floor(sy), fx = floor(sx);
  double wy = sy - fy,   wx = sx - fx;
  int y0 = (int)fy, x0 = (int)fx;
  int y0i = min(max(y0,   0), 31), y1i = min(max(y0+1, 0), 31);
  int x0i = min(max(x0,   0), 31), x1i = min(max(x0+1, 0), 31);
  const double* s = s32 + b*1024;
  double v00 = s[y0i*32+x0i], v01 = s[y0i*32+x1i];
  double v10 = s[y1i*32+x0i], v11 = s[y1i*32+x1i];
  return v00*(1.0-wy)*(1.0-wx) + v01*(1.0-wy)*wx
       + v10*wy*(1.0-wx)       + v11*wy*wx;
}

// ---------------------------------------------------------------------------
// Stage 2a: global bad-pixel sum/count (f64) + bad bitmap (ballot-packed)
// ---------------------------------------------------------------------------
__global__ __launch_bounds__(256) void mean_k(
    const float* __restrict__ xhat, const double* __restrict__ s32,
    double* __restrict__ sum, unsigned long long* __restrict__ cnt,
    unsigned long long* __restrict__ bitmap)
{
  int id = blockIdx.x*256 + threadIdx.x;
  int b = id >> 18, rem = id & (IMGPIX-1);
  int oy = rem >> 9, ox = rem & 511;
  double ps = upsample_ps(s32, b, oy, ox);
  bool bad = ps < 0.5;
  int lane = threadIdx.x & 63;
  unsigned long long bb = __ballot(bad);
  if (lane == 0) bitmap[id >> 6] = bb;
  double v = bad ? (double)xhat[id] : 0.0;
  int    c = bad ? 1 : 0;
  for (int off = 32; off; off >>= 1) {
    v += __shfl_down(v, off);
    c += __shfl_down(c, off);
  }
  __shared__ double sv[4];
  __shared__ int    sc[4];
  int w = threadIdx.x >> 6;
  if (lane == 0) { sv[w] = v; sc[w] = c; }
  __syncthreads();
  if (threadIdx.x == 0) {
    atomicAdd(sum, sv[0]+sv[1]+sv[2]+sv[3]);
    atomicAdd(cnt, (unsigned long long)(sc[0]+sc[1]+sc[2]+sc[3]));
  }
}

// Stage 2b: belief map + row max fused (block = one row of 512 px)
__global__ __launch_bounds__(512) void bmrow_k(
    const float* __restrict__ xhat, const unsigned long long* __restrict__ bitmap,
    const double* __restrict__ sum, const unsigned long long* __restrict__ cnt,
    float* __restrict__ bm, float* __restrict__ rm)
{
  __shared__ float row[512];
  int tid = threadIdx.x;
  int id = blockIdx.x*512 + tid;
  unsigned long long wrd = bitmap[id >> 6];
  bool bad = (wrd >> (id & 63)) & 1ull;
  unsigned long long n = *cnt; if (n < 1) n = 1;
  float mean = (float)(*sum / (double)n);
  float v = bad ? mean : xhat[id];
  bm[id] = v; row[tid] = v;
  __syncthreads();
  int lo = max(tid-3, 0), hi = min(tid+3, 511);
  float m = row[lo];
  for (int xx = lo+1; xx <= hi; ++xx) m = fmaxf(m, row[xx]);
  rm[id] = m;
}

// ---------------------------------------------------------------------------
// Stage 2c: column max + key gen + fused radix pass-0 histogram (bin=key>>36)
// Keys: cand ? (fbits<<18)|inv : inv   (48-bit, distinct per pixel)
// ---------------------------------------------------------------------------
__global__ __launch_bounds__(512) void keys_k(
    const float* __restrict__ bm, const float* __restrict__ rm,
    unsigned long long* __restrict__ keys, unsigned int* __restrict__ hist0)
{
  __shared__ unsigned int lh[4096];
  const int tid = threadIdx.x;
  for (int i = tid; i < 4096; i += 512) lh[i] = 0;
  int id = blockIdx.x*512 + tid;
  int rem = id & (IMGPIX-1);
  int x = rem & 511, y = rem >> 9;
  int imgbase = id - rem;
  int lo = max(y-3, 0), hi = min(y+3, 511);
  float mp = rm[imgbase + (lo<<9) + x];
  for (int yy = lo+1; yy <= hi; ++yy) mp = fmaxf(mp, rm[imgbase + (yy<<9) + x]);
  float v = bm[id];
  bool cand = (v == mp) && (v > NMS_THR);
  unsigned int inv = (unsigned int)((IMGPIX-1) - rem);
  unsigned long long key = cand
      ? ((((unsigned long long)__float_as_uint(v)) << 18) | inv)
      : (unsigned long long)inv;
  keys[id] = key;
  __syncthreads();
  int bin = (int)(key >> 36);
  int lane = tid & 63;
  unsigned long long active = ~0ull;
  while (active) {
    int src = __ffsll((long long)active) - 1;
    int bsel = __shfl(bin, src);
    unsigned long long match = __ballot(bin == bsel) & active;
    if (lane == src) atomicAdd(&lh[bsel], (unsigned int)__popcll(match));
    active &= ~match;
  }
  __syncthreads();
  int img = blockIdx.x >> 9;
  for (int i = tid; i < 4096; i += 512)
    if (lh[i]) atomicAdd(&hist0[img*4096 + i], lh[i]);
}

// Radix histogram pass p>=1
__global__ __launch_bounds__(512) void hist_k(
    const unsigned long long* __restrict__ keys,
    const unsigned long long* __restrict__ pfx,
    unsigned int* __restrict__ hist, int shift)
{
  __shared__ unsigned int lh[4096];
  const int tid = threadIdx.x;
  for (int i = tid; i < 4096; i += 512) lh[i] = 0;
  int id = blockIdx.x*512 + tid;
  int img = blockIdx.x >> 9;
  unsigned long long key = keys[id];
  bool pred = (key >> (shift + 12)) == pfx[img];
  int bin = (int)((unsigned int)(key >> shift) & 4095u);
  __syncthreads();
  int lane = tid & 63;
  unsigned long long active = __ballot(pred);
  while (active) {
    int src = __ffsll((long long)active) - 1;
    int bsel = __shfl(bin, src);
    unsigned long long match = __ballot(bin == bsel) & active;
    if (lane == src) atomicAdd(&lh[bsel], (unsigned int)__popcll(match));
    active &= ~match;
  }
  __syncthreads();
  for (int i = tid; i < 4096; i += 512)
    if (lh[i]) atomicAdd(&hist[img*4096 + i], lh[i]);
}

// Scan 4096-bin histogram (suffix sums), find cut digit, update pfx/R
__global__ __launch_bounds__(512) void scan_k(
    const unsigned int* __restrict__ hist,
    unsigned long long* __restrict__ pfx, unsigned int* __restrict__ Rbuf,
    int pass)
{
  __shared__ unsigned int lsA[512], lsB[512];
  const int b = blockIdx.x, tid = threadIdx.x;
  unsigned long long pin = (pass == 0) ? 0ull : pfx[b];
  unsigned int Rin = (pass == 0) ? (unsigned int)KSEL : Rbuf[b];
  const unsigned int* h = hist + b*4096;
  unsigned int v[8]; unsigned int loc = 0;
#pragma unroll
  for (int j = 0; j < 8; ++j) { v[j] = h[tid*8 + j]; loc += v[j]; }
  lsA[tid] = loc;
  __syncthreads();
  unsigned int* s = lsA; unsigned int* d = lsB;
  for (int dd = 1; dd < 512; dd <<= 1) {
    unsigned int val = s[tid] + ((tid + dd < 512) ? s[tid + dd] : 0u);
    d[tid] = val;
    __syncthreads();
    unsigned int* t = s; s = d; d = t;
  }
  unsigned int nxt = (tid + 1 < 512) ? s[tid + 1] : 0u;  // suffix of later chunks
#pragma unroll
  for (int j = 7; j >= 0; --j) {
    unsigned int sfx = nxt + v[j];
    if (sfx >= Rin && nxt < Rin) {
      pfx[b] = (pin << 12) | (unsigned long long)(unsigned int)(tid*8 + j);
      Rbuf[b] = Rin - nxt;
    }
    nxt = sfx;
  }
}

// Collect the 512 keys >= cutkey (exactly 512: keys distinct, cut = rank-512)
__global__ __launch_bounds__(512) void collect_k(
    const unsigned long long* __restrict__ keys,
    const unsigned long long* __restrict__ pfx,
    unsigned int* __restrict__ ccnt, unsigned long long* __restrict__ sel)
{
  int id = blockIdx.x*512 + threadIdx.x;
  int img = blockIdx.x >> 9;
  unsigned long long key = keys[id];
  if (key >= pfx[img]) {
    unsigned int pos = atomicAdd(&ccnt[img], 1u);
    if (pos < 512) sel[img*512 + pos] = key;
  }
}

// Bitonic sort 512 (desc) + write coords/top_s/valid/props
__global__ __launch_bounds__(512) void sortout_k(
    const unsigned long long* __restrict__ sel,
    float* __restrict__ out, int* __restrict__ props)
{
  __shared__ unsigned long long s[512];
  const int b = blockIdx.x, tid = threadIdx.x;
  s[tid] = sel[b*512 + tid];
  __syncthreads();
  for (int size = 2; size <= 512; size <<= 1) {
    for (int stride = size >> 1; stride > 0; stride >>= 1) {
      int j = tid ^ stride;
      if (j > tid) {
        unsigned long long a = s[tid], c = s[j];
        bool up = ((tid & size) == 0);
        if (up ? (a < c) : (a > c)) { s[tid] = c; s[j] = a; }
      }
      __syncthreads();
    }
  }
  unsigned long long k = s[tid];
  unsigned int fbits = (unsigned int)(k >> 18);
  int idx = (IMGPIX-1) - (int)(k & 0x3FFFFull);
  int y = idx >> 9, x = idx & 511;
  float val = fbits ? __uint_as_float(fbits) : -INFINITY;
  int slot = (b << 9) + tid;
  out[12288 + slot]       = val;
  out[8192 + slot*2 + 0]  = (float)x;
  out[8192 + slot*2 + 1]  = (float)y;
  out[14336 + slot]       = (val > NMS_THR) ? 1.0f : 0.0f;
  props[slot*2 + 0] = x;
  props[slot*2 + 1] = y;
}

// ---------------------------------------------------------------------------
// Weight repack (all 3 layers, one launch):
// qw[oc][ic][ky][kx] f32 -> [tap][kstep][oc][32] f16
// ---------------------------------------------------------------------------
__global__ void repack_all_k(
    const float* __restrict__ qw1, const float* __restrict__ qw2,
    const float* __restrict__ qw3,
    half_t* __restrict__ W1, half_t* __restrict__ W2, half_t* __restrict__ W3)
{
  const int tot1 = 256*64*9, tot2 = 256*256*9;
  int idx = blockIdx.x*256 + threadIdx.x;
  const float* src; half_t* dst; int IC, KS, l;
  if (idx < tot1)              { src = qw1; dst = W1; IC = 64;  KS = 2; l = idx; }
  else if (idx < tot1 + tot2)  { src = qw2; dst = W2; IC = 256; KS = 8; l = idx - tot1; }
  else if (idx < tot1 + 2*tot2){ src = qw3; dst = W3; IC = 256; KS = 8; l = idx - tot1 - tot2; }
  else return;
  int tap = l % 9;
  int t   = l / 9;
  int ic  = t % IC;
  int oc  = t / IC;
  int ks  = ic >> 5, kin = ic & 31;
  dst[((size_t)(tap*KS + ks)*256 + oc)*32 + kin] = (half_t)src[l];
}

// ---------------------------------------------------------------------------
// Stage 3+4 (MFMA): 2 proposals per block, 512 thr = 8 waves.
// Wave = (mg in {0,1}) x (ng in 0..3): mg owns oc [128mg,128mg+128) (8 Mtiles),
// ng -> proposal pj=ng>>1, px half nh=ng&1 (px [32nh,32nh+32), 2 Ntiles).
// A (weights) from global (L1-shared across the 4 sibling waves),
// B (activations) from LDS: X2[pj*64+px][ic] stride 264, zero row 128.
// ---------------------------------------------------------------------------
#define SA2 264
#define SA1 72

template<int KS, int SA>
__device__ __forceinline__ void conv_mfma2(
    const half_t* __restrict__ Wl, const half_t* __restrict__ Xin,
    int rowbase, int zrow, int pxb, int mgbase, int quad, int c15,
    f32x4 acc[8][2])
{
#pragma unroll
  for (int mt = 0; mt < 8; ++mt)
#pragma unroll
    for (int nt = 0; nt < 2; ++nt) acc[mt][nt] = (f32x4){0.f,0.f,0.f,0.f};

  for (int tap = 0; tap < 9; ++tap) {
    const int dy = tap/3 - 1, dx = tap%3 - 1;
    int xoff[2];
#pragma unroll
    for (int nt = 0; nt < 2; ++nt) {
      int px = pxb + nt*16 + c15;
      int y = px/7, x = px - y*7;
      int yy = y + dy, xx = x + dx;
      bool valid = (px < 49) & (yy >= 0) & (yy < 7) & (xx >= 0) & (xx < 7);
      int row = valid ? (rowbase + yy*7 + xx) : zrow;
      xoff[nt] = row*SA + quad*8;
    }
    const half_t* wb = Wl + ((size_t)(tap*KS)*256 + mgbase + c15)*32 + quad*8;
#pragma unroll 2
    for (int ks = 0; ks < KS; ++ks) {
      half8 bfr[2];
#pragma unroll
      for (int nt = 0; nt < 2; ++nt)
        bfr[nt] = *(const half8*)(Xin + xoff[nt] + ks*32);
      half8 afr[8];
#pragma unroll
      for (int mt = 0; mt < 8; ++mt)
        afr[mt] = *(const half8*)(wb + (size_t)(ks*256 + mt*16)*32);
#pragma unroll
      for (int mt = 0; mt < 8; ++mt)
#pragma unroll
        for (int nt = 0; nt < 2; ++nt)
          acc[mt][nt] = __builtin_amdgcn_mfma_f32_16x16x32_f16(
              afr[mt], bfr[nt], acc[mt][nt], 0, 0, 0);
    }
  }
}

__device__ __forceinline__ void store_layer2(
    half_t* __restrict__ X2p, const float* __restrict__ bias,
    int pxb, int mgbase, int quad, int c15, f32x4 acc[8][2])
{
#pragma unroll
  for (int mt = 0; mt < 8; ++mt) {
    int ocb = mgbase + mt*16 + quad*4;
#pragma unroll
    for (int nt = 0; nt < 2; ++nt) {
      int px = pxb + nt*16 + c15;
      half4 h;
#pragma unroll
      for (int r = 0; r < 4; ++r) {
        float v = acc[mt][nt][r] + bias[ocb + r];
        h[r] = (half_t)LRELU_F(v);
      }
      *(half4*)(X2p + px*SA2 + ocb) = h;
    }
  }
}

__global__ __launch_bounds__(512) void head_k(
    const float* __restrict__ fup, const int* __restrict__ props,
    const half_t* __restrict__ W1, const half_t* __restrict__ W2,
    const half_t* __restrict__ W3,
    const float* __restrict__ qb1, const float* __restrict__ qb2,
    const float* __restrict__ qb3,
    const float* __restrict__ qfcw, const float* __restrict__ qfcb,
    float* __restrict__ out)
{
  __shared__ __align__(16) half_t X2[129*SA2];   // 68112 B; rows 0..127 acts, 128 zero
  __shared__ __align__(16) char  U[99*SA1*2];    // X1 (conv1 input) / S (epilogue)
  half_t* X1 = (half_t*)U;                       // rows 0..97 acts, 98 zero
  float*  S  = (float*)U;                        // [2 pj][2 nh][256 oc]

  const int p0 = blockIdx.x*2;
  const int b  = p0 >> 9;
  const int tid = threadIdx.x;
  const int w = tid >> 6, lane = tid & 63;
  const int quad = lane >> 4, c15 = lane & 15;
  const int mg = w >> 2, ng = w & 3;
  const int pj = ng >> 1, nh = ng & 1;

  for (int i = tid; i < SA2; i += 512) X2[128*SA2 + i] = (half_t)0.f;
  for (int i = tid; i < SA1; i += 512) X1[98*SA1 + i] = (half_t)0.f;

  // ROI-align for both proposals (exact reference arithmetic)
  const float step = (float)(10.0/7.0);
  for (int it = tid; it < 2*CUP*49; it += 512) {
    int pp = it / (CUP*49), rem2 = it - pp*(CUP*49);
    int c = rem2 / 49, bin = rem2 - c*49;
    int iy = bin / 7, ix = bin - iy*7;
    int cx = props[2*(p0+pp)], cy = props[2*(p0+pp)+1];
    float fy = ((float)cy - 5.0f) + ((float)iy + 0.5f)*step;
    float fx = ((float)cx - 5.0f) + ((float)ix + 0.5f)*step;
    float y0f = floorf(fy), x0f = floorf(fx);
    float wy = fy - y0f,    wx = fx - x0f;
    int y0 = (int)y0f, x0 = (int)x0f;
    int y0i = min(max(y0,   0), 511), y1i = min(max(y0+1, 0), 511);
    int x0i = min(max(x0,   0), 511), x1i = min(max(x0+1, 0), 511);
    const float* f = fup + ((size_t)(b*CUP + c) << 18);
    float v00 = f[(y0i<<9)+x0i], v01 = f[(y0i<<9)+x1i];
    float v10 = f[(y1i<<9)+x0i], v11 = f[(y1i<<9)+x1i];
    float v = v00*(1.f-wy)*(1.f-wx) + v01*(1.f-wy)*wx
            + v10*wy*(1.f-wx)       + v11*wy*wx;
    X1[(pp*49 + iy*7 + ix)*SA1 + c] = (half_t)v;
  }
  __syncthreads();

  f32x4 acc[8][2];

  // conv1: ic=64 (no barrier needed before store: X1->X2 disjoint)
  conv_mfma2<2, SA1>(W1, X1, pj*49, 98, nh*32, mg*128, quad, c15, acc);
  store_layer2(X2 + pj*64*SA2, qb1, nh*32, mg*128, quad, c15, acc);
  __syncthreads();

  // conv2: ic=256, in-place
  conv_mfma2<8, SA2>(W2, X2, pj*64, 128, nh*32, mg*128, quad, c15, acc);
  __syncthreads();
  store_layer2(X2 + pj*64*SA2, qb2, nh*32, mg*128, quad, c15, acc);
  __syncthreads();

  // conv3 + bias + leaky + spatial max
  conv_mfma2<8, SA2>(W3, X2, pj*64, 128, nh*32, mg*128, quad, c15, acc);
#pragma unroll
  for (int mt = 0; mt < 8; ++mt) {
#pragma unroll
    for (int r = 0; r < 4; ++r) {
      int oc = mg*128 + mt*16 + quad*4 + r;
      float bv = qb3[oc];
      float m = -3.4e38f;
#pragma unroll
      for (int nt = 0; nt < 2; ++nt) {
        int px = nh*32 + nt*16 + c15;
        float v = acc[mt][nt][r] + bv;
        v = LRELU_F(v);
        m = (px < 49) ? fmaxf(m, v) : m;
      }
#pragma unroll
      for (int d = 1; d < 16; d <<= 1) m = fmaxf(m, __shfl_xor(m, d));
      if (c15 == 0) S[(pj*2 + nh)*256 + oc] = m;
    }
  }
  __syncthreads();

  // FC 256 -> 4 per proposal (P reuses X2: all conv3 reads drained above)
  float* P = (float*)X2;   // [8][256]  (prop*4 + j)
  {
    int pj2 = tid >> 8, oc = tid & 255;
    float h = fmaxf(S[(pj2*2 + 0)*256 + oc], S[(pj2*2 + 1)*256 + oc]);
#pragma unroll
    for (int j = 0; j < 4; ++j) P[(pj2*4 + j)*256 + oc] = h * qfcw[j*256 + oc];
  }
  __syncthreads();
  {
    int sseg = tid >> 6, o = tid & 63;
    float v = P[sseg*256 + o] + P[sseg*256 + o + 64]
            + P[sseg*256 + o + 128] + P[sseg*256 + o + 192];
#pragma unroll
    for (int d = 1; d < 64; d <<= 1) v += __shfl_xor(v, d);
    if (o == 0) {
      int pg = p0 + (sseg >> 2), j = sseg & 3;
      out[pg*4 + j] = v + qfcb[j];
    }
  }
}

// ---------------------------------------------------------------------------
extern "C" void kernel_launch(void* const* d_in, const int* in_sizes, int n_in,
                              void* d_out, int out_size, void* d_ws, size_t ws_size,
                              hipStream_t stream)
{
  (void)in_sizes; (void)n_in; (void)out_size; (void)ws_size;
  const float* xhat  = (const float*)d_in[0];
  const float* fdown = (const float*)d_in[1];
  const float* fup   = (const float*)d_in[2];
  const float* pw1   = (const float*)d_in[3];
  const float* pb1   = (const float*)d_in[4];
  const float* pw2   = (const float*)d_in[5];
  const float* pb2   = (const float*)d_in[6];
  const float* pw3   = (const float*)d_in[7];
  const float* pb3   = (const float*)d_in[8];
  const float* pfcw  = (const float*)d_in[9];
  const float* pfcb  = (const float*)d_in[10];
  const float* qw1   = (const float*)d_in[11];
  const float* qb1   = (const float*)d_in[12];
  const float* qw2   = (const float*)d_in[13];
  const float* qb2   = (const float*)d_in[14];
  const float* qw3   = (const float*)d_in[15];
  const float* qb3   = (const float*)d_in[16];
  const float* qfcw  = (const float*)d_in[17];
  const float* qfcb  = (const float*)d_in[18];

  char* ws = (char*)d_ws;
  double*             s32   = (double*)(ws + OFF_S32);
  double*             sum   = (double*)(ws + OFF_SUM);
  unsigned long long* cnt   = (unsigned long long*)(ws + OFF_CNT);
  unsigned int*       ccnt  = (unsigned int*)(ws + OFF_CCNT);
  unsigned int*       hist  = (unsigned int*)(ws + OFF_HIST);
  unsigned long long* pfx   = (unsigned long long*)(ws + OFF_PFX);
  unsigned int*       Rbuf  = (unsigned int*)(ws + OFF_R);
  unsigned long long* bmap  = (unsigned long long*)(ws + OFF_BITMAP);
  float*              bm    = (float*)(ws + OFF_BM);
  float*              rm    = (float*)(ws + OFF_RM);
  unsigned long long* keys  = (unsigned long long*)(ws + OFF_KEYS);
  unsigned long long* sel   = (unsigned long long*)(ws + OFF_SEL);
  int*                props = (int*)(ws + OFF_PROPS);
  half_t*             Wp1   = (half_t*)(ws + OFF_W1);
  half_t*             Wp2   = (half_t*)(ws + OFF_W2);
  half_t*             Wp3   = (half_t*)(ws + OFF_W3);
  float*              out   = (float*)d_out;

  hipMemsetAsync(ws + ZERO_BASE, 0, ZERO_LEN, stream);

  const int tot = 256*64*9 + 2*256*256*9;
  repack_all_k<<<(tot + 255)/256, 256, 0, stream>>>(qw1, qw2, qw3, Wp1, Wp2, Wp3);

  patch_k <<<512, 256, 0, stream>>>(fdown, pw1,pb1, pw2,pb2, pw3,pb3, pfcw,pfcb, s32);
  mean_k  <<<4096, 256, 0, stream>>>(xhat, s32, sum, cnt, bmap);
  bmrow_k <<<2048, 512, 0, stream>>>(xhat, bmap, sum, cnt, bm, rm);
  keys_k  <<<2048, 512, 0, stream>>>(bm, rm, keys, hist + 0*4*4096);
  scan_k  <<<BB, 512, 0, stream>>>(hist + 0*4*4096, pfx, Rbuf, 0);
  hist_k  <<<2048, 512, 0, stream>>>(keys, pfx, hist + 1*4*4096, 24);
  scan_k  <<<BB, 512, 0, stream>>>(hist + 1*4*4096, pfx, Rbuf, 1);
  hist_k  <<<2048, 512, 0, stream>>>(keys, pfx, hist + 2*4*4096, 12);
  scan_k  <<<BB, 512, 0, stream>>>(hist + 2*4*4096, pfx, Rbuf, 2);
  hist_k  <<<2048, 512, 0, stream>>>(keys, pfx, hist + 3*4*4096, 0);
  scan_k  <<<BB, 512, 0, stream>>>(hist + 3*4*4096, pfx, Rbuf, 3);
  collect_k<<<2048, 512, 0, stream>>>(keys, pfx, ccnt, sel);
  sortout_k<<<BB, 512, 0, stream>>>(sel, out, props);

  head_k  <<<NPROP/2, 512, 0, stream>>>(fup, props, Wp1, Wp2, Wp3,
                                        qb1, qb2, qb3, qfcw, qfcb, out);
}

// Round 4
// 951.339 us; speedup vs baseline: 1.5631x; 1.5631x over previous
//
#include <hip/hip_runtime.h>
#include <math.h>

typedef _Float16 half_t;
typedef half_t half8 __attribute__((ext_vector_type(8)));
typedef half_t half4 __attribute__((ext_vector_type(4)));
typedef float  f32x16 __attribute__((ext_vector_type(16)));
typedef double dbl2  __attribute__((ext_vector_type(2)));

// Problem constants
#define BB 4
#define HH 512
#define WW 512
#define IMGPIX (HH*WW)        // 262144
#define KSEL 512
#define NPROP (BB*KSEL)       // 2048
#define CUP 64
#define NMS_THR 0.2f

// Workspace layout (bytes)
#define OFF_S32    0                      // double[4096] = 32768
#define OFF_SUM    32768                  // double
#define OFF_CNT    32776                  // ull
#define OFF_CCNT   32784                  // u32[4]
#define OFF_HIST   32800                  // u32[4][4][4096] = 262144
#define ZERO_BASE  32768
#define ZERO_LEN   262176                 // sum..hist inclusive
#define OFF_PFX    294944                 // ull[4]
#define OFF_R      294976                 // u32[4] (+pad)
#define OFF_BITMAP 295040                 // u64[16384] = 131072
#define OFF_KEYS   426112                 // u64[1048576] = 8 MB -> 8814720
#define OFF_SEL    8814720                // u64[2048]
#define OFF_PROPS  8831104                // int[4096]
#define OFF_W1     8847488                // 294912
#define OFF_W2     9142400                // 1179648
#define OFF_W3     10322048               // 1179648 -> 11501696 total

#define LRELU_F(x) ((x) > 0.0f ? (x) : 0.1f*(x))

// ---------------------------------------------------------------------------
// Stage 1 (+fused weight repack): blocks 0..511 = patch MLP, rest = repack
// Repack: qw[oc][ic][3][3] f32 -> [tap][ks(ic/16)][oc][16] f16
// ---------------------------------------------------------------------------
__global__ __launch_bounds__(256) void repatch_k(
    const float* __restrict__ fdown,
    const float* __restrict__ pw1, const float* __restrict__ pb1,
    const float* __restrict__ pw2, const float* __restrict__ pb2,
    const float* __restrict__ pw3, const float* __restrict__ pb3,
    const float* __restrict__ pfcw, const float* __restrict__ pfcb,
    double* __restrict__ s32,
    const float* __restrict__ qw1, const float* __restrict__ qw2,
    const float* __restrict__ qw3,
    half_t* __restrict__ W1, half_t* __restrict__ W2, half_t* __restrict__ W3)
{
  if (blockIdx.x >= 512) {
    const int tot1 = 256*64*9, tot2 = 256*256*9;
    int idx = (blockIdx.x - 512)*256 + threadIdx.x;
    const float* src; half_t* dst; int IC, KS, l;
    if (idx < tot1)              { src = qw1; dst = W1; IC = 64;  KS = 4;  l = idx; }
    else if (idx < tot1 + tot2)  { src = qw2; dst = W2; IC = 256; KS = 16; l = idx - tot1; }
    else if (idx < tot1 + 2*tot2){ src = qw3; dst = W3; IC = 256; KS = 16; l = idx - tot1 - tot2; }
    else return;
    int tap = l % 9;
    int t   = l / 9;
    int ic  = t % IC;
    int oc  = t / IC;
    int ks  = ic >> 4, kin = ic & 15;
    dst[((size_t)(tap*KS + ks)*256 + oc)*16 + kin] = (half_t)src[l];
    return;
  }
  __shared__ __align__(16) double xb[8][256];
  const int t = threadIdx.x;
  const int base_px = blockIdx.x * 8;
#pragma unroll
  for (int p = 0; p < 8; ++p) {
    int px = base_px + p;
    int b = px >> 10, rem = px & 1023;
    xb[p][t] = (double)fdown[(size_t)(b*256 + t)*1024 + rem];
  }
  __syncthreads();
  const float* Ws[3] = {pw1, pw2, pw3};
  const float* Bs[3] = {pb1, pb2, pb3};
  for (int L = 0; L < 3; ++L) {
    double acc[8];
    double bias = (double)Bs[L][t];
#pragma unroll
    for (int p = 0; p < 8; ++p) acc[p] = bias;
    const float* wrow = Ws[L] + t*256;
    for (int c = 0; c < 256; c += 2) {
      double w0 = (double)wrow[c], w1 = (double)wrow[c+1];
#pragma unroll
      for (int p = 0; p < 8; ++p) {
        dbl2 xv = *(const dbl2*)&xb[p][c];
        acc[p] += w0 * xv.x;
        acc[p] += w1 * xv.y;
      }
    }
    __syncthreads();
#pragma unroll
    for (int p = 0; p < 8; ++p)
      xb[p][t] = acc[p] > 0.0 ? acc[p] : 0.1*acc[p];
    __syncthreads();
  }
  if (t < 8) {
    double l0 = (double)pfcb[0], l1 = (double)pfcb[1];
    for (int c = 0; c < 256; ++c) {
      double xv = xb[t][c];
      l0 += (double)pfcw[c]       * xv;
      l1 += (double)pfcw[256 + c] * xv;
    }
    double m  = fmax(l0, l1);
    double e0 = exp(l0 - m), e1 = exp(l1 - m);
    s32[base_px + t] = e1 / (e0 + e1);
  }
}

// Bilinear upsample 32->512 (align_corners=False), matches jax.image.resize.
__device__ __forceinline__ double upsample_ps(const double* __restrict__ s32,
                                              int b, int oy, int ox)
{
  double sy = (oy + 0.5)*0.0625 - 0.5;
  double sx = (ox + 0.5)*0.0625 - 0.5;
  double fy = floor(sy), fx = floor(sx);
  double wy = sy - fy,   wx = sx - fx;
  int y0 = (int)fy, x0 = (int)fx;
  int y0i = min(max(y0,   0), 31), y1i = min(max(y0+1, 0), 31);
  int x0i = min(max(x0,   0), 31), x1i = min(max(x0+1, 0), 31);
  const double* s = s32 + b*1024;
  double v00 = s[y0i*32+x0i], v01 = s[y0i*32+x1i];
  double v10 = s[y1i*32+x0i], v11 = s[y1i*32+x1i];
  return v00*(1.0-wy)*(1.0-wx) + v01*(1.0-wy)*wx
       + v10*wy*(1.0-wx)       + v11*wy*wx;
}

// ---------------------------------------------------------------------------
// Stage 2a: global bad-pixel sum/count (f64) + bad bitmap (ballot-packed)
// ---------------------------------------------------------------------------
__global__ __launch_bounds__(256) void mean_k(
    const float* __restrict__ xhat, const double* __restrict__ s32,
    double* __restrict__ sum, unsigned long long* __restrict__ cnt,
    unsigned long long* __restrict__ bitmap)
{
  int id = blockIdx.x*256 + threadIdx.x;
  int b = id >> 18, rem = id & (IMGPIX-1);
  int oy = rem >> 9, ox = rem & 511;
  double ps = upsample_ps(s32, b, oy, ox);
  bool bad = ps < 0.5;
  int lane = threadIdx.x & 63;
  unsigned long long bb = __ballot(bad);
  if (lane == 0) bitmap[id >> 6] = bb;
  double v = bad ? (double)xhat[id] : 0.0;
  int    c = bad ? 1 : 0;
  for (int off = 32; off; off >>= 1) {
    v += __shfl_down(v, off);
    c += __shfl_down(c, off);
  }
  __shared__ double sv[4];
  __shared__ int    sc[4];
  int w = threadIdx.x >> 6;
  if (lane == 0) { sv[w] = v; sc[w] = c; }
  __syncthreads();
  if (threadIdx.x == 0) {
    atomicAdd(sum, sv[0]+sv[1]+sv[2]+sv[3]);
    atomicAdd(cnt, (unsigned long long)(sc[0]+sc[1]+sc[2]+sc[3]));
  }
}

// ---------------------------------------------------------------------------
// Stage 2b (fused): belief map + 7x7 NMS + keys + radix pass-0 histogram.
// Block = 8 rows of one image (+3-row halo recomputed). No bm/rm arrays.
// ---------------------------------------------------------------------------
__global__ __launch_bounds__(512) void keyfuse_k(
    const float* __restrict__ xhat, const unsigned long long* __restrict__ bitmap,
    const double* __restrict__ sum, const unsigned long long* __restrict__ cnt,
    unsigned long long* __restrict__ keys, unsigned int* __restrict__ hist0)
{
  __shared__ float rowm[14][512];
  __shared__ float bmv[8][512];
  __shared__ float rt[512];
  __shared__ unsigned int lh[4096];
  const int tid = threadIdx.x;
  const int img = blockIdx.x >> 6;
  const int rb  = (blockIdx.x & 63) * 8;
  for (int i = tid; i < 4096; i += 512) lh[i] = 0;

  unsigned long long n = *cnt; if (n < 1) n = 1;
  const float mean = (float)(*sum / (double)n);
  const int ibase = img * IMGPIX;

  for (int r = 0; r < 14; ++r) {
    int y = rb - 3 + r;
    float v = -INFINITY;
    if (y >= 0 && y < 512) {
      int id = ibase + (y << 9) + tid;
      bool bad = (bitmap[id >> 6] >> (id & 63)) & 1ull;
      v = bad ? mean : xhat[id];
    }
    int cr = y - rb;
    if (cr >= 0 && cr < 8) bmv[cr][tid] = v;
    rt[tid] = v;
    __syncthreads();
    int lo = max(tid-3, 0), hi = min(tid+3, 511);
    float m = rt[lo];
    for (int xx = lo+1; xx <= hi; ++xx) m = fmaxf(m, rt[xx]);
    rowm[r][tid] = m;
    __syncthreads();
  }

  const int lane = tid & 63;
  for (int yy = 0; yy < 8; ++yy) {
    float mp = rowm[yy][tid];
#pragma unroll
    for (int d = 1; d < 7; ++d) mp = fmaxf(mp, rowm[yy + d][tid]);
    float v = bmv[yy][tid];
    bool cand = (v == mp) && (v > NMS_THR);
    int rem = ((rb + yy) << 9) + tid;
    unsigned int inv = (unsigned int)((IMGPIX-1) - rem);
    unsigned long long key = cand
        ? ((((unsigned long long)__float_as_uint(v)) << 18) | inv)
        : (unsigned long long)inv;
    keys[ibase + rem] = key;
    int bin = (int)(key >> 36);
    unsigned long long active = ~0ull;
    while (active) {
      int src = __ffsll((long long)active) - 1;
      int bsel = __shfl(bin, src);
      unsigned long long match = __ballot(bin == bsel) & active;
      if (lane == src) atomicAdd(&lh[bsel], (unsigned int)__popcll(match));
      active &= ~match;
    }
  }
  __syncthreads();
  for (int i = tid; i < 4096; i += 512)
    if (lh[i]) atomicAdd(&hist0[img*4096 + i], lh[i]);
}

// Radix histogram pass p>=1
__global__ __launch_bounds__(512) void hist_k(
    const unsigned long long* __restrict__ keys,
    const unsigned long long* __restrict__ pfx,
    unsigned int* __restrict__ hist, int shift)
{
  __shared__ unsigned int lh[4096];
  const int tid = threadIdx.x;
  for (int i = tid; i < 4096; i += 512) lh[i] = 0;
  int id = blockIdx.x*512 + tid;
  int img = blockIdx.x >> 9;
  unsigned long long key = keys[id];
  bool pred = (key >> (shift + 12)) == pfx[img];
  int bin = (int)((unsigned int)(key >> shift) & 4095u);
  __syncthreads();
  int lane = tid & 63;
  unsigned long long active = __ballot(pred);
  while (active) {
    int src = __ffsll((long long)active) - 1;
    int bsel = __shfl(bin, src);
    unsigned long long match = __ballot(bin == bsel) & active;
    if (lane == src) atomicAdd(&lh[bsel], (unsigned int)__popcll(match));
    active &= ~match;
  }
  __syncthreads();
  for (int i = tid; i < 4096; i += 512)
    if (lh[i]) atomicAdd(&hist[img*4096 + i], lh[i]);
}

// Scan 4096-bin histogram (suffix sums), find cut digit, update pfx/R
__global__ __launch_bounds__(512) void scan_k(
    const unsigned int* __restrict__ hist,
    unsigned long long* __restrict__ pfx, unsigned int* __restrict__ Rbuf,
    int pass)
{
  __shared__ unsigned int lsA[512], lsB[512];
  const int b = blockIdx.x, tid = threadIdx.x;
  unsigned long long pin = (pass == 0) ? 0ull : pfx[b];
  unsigned int Rin = (pass == 0) ? (unsigned int)KSEL : Rbuf[b];
  const unsigned int* h = hist + b*4096;
  unsigned int v[8]; unsigned int loc = 0;
#pragma unroll
  for (int j = 0; j < 8; ++j) { v[j] = h[tid*8 + j]; loc += v[j]; }
  lsA[tid] = loc;
  __syncthreads();
  unsigned int* s = lsA; unsigned int* d = lsB;
  for (int dd = 1; dd < 512; dd <<= 1) {
    unsigned int val = s[tid] + ((tid + dd < 512) ? s[tid + dd] : 0u);
    d[tid] = val;
    __syncthreads();
    unsigned int* t = s; s = d; d = t;
  }
  unsigned int nxt = (tid + 1 < 512) ? s[tid + 1] : 0u;
#pragma unroll
  for (int j = 7; j >= 0; --j) {
    unsigned int sfx = nxt + v[j];
    if (sfx >= Rin && nxt < Rin) {
      pfx[b] = (pin << 12) | (unsigned long long)(unsigned int)(tid*8 + j);
      Rbuf[b] = Rin - nxt;
    }
    nxt = sfx;
  }
}

// Collect the 512 keys >= cutkey (exactly 512: keys distinct, cut = rank-512)
__global__ __launch_bounds__(512) void collect_k(
    const unsigned long long* __restrict__ keys,
    const unsigned long long* __restrict__ pfx,
    unsigned int* __restrict__ ccnt, unsigned long long* __restrict__ sel)
{
  int id = blockIdx.x*512 + threadIdx.x;
  int img = blockIdx.x >> 9;
  unsigned long long key = keys[id];
  if (key >= pfx[img]) {
    unsigned int pos = atomicAdd(&ccnt[img], 1u);
    if (pos < 512) sel[img*512 + pos] = key;
  }
}

// Bitonic sort 512 (desc) + write coords/top_s/valid/props
__global__ __launch_bounds__(512) void sortout_k(
    const unsigned long long* __restrict__ sel,
    float* __restrict__ out, int* __restrict__ props)
{
  __shared__ unsigned long long s[512];
  const int b = blockIdx.x, tid = threadIdx.x;
  s[tid] = sel[b*512 + tid];
  __syncthreads();
  for (int size = 2; size <= 512; size <<= 1) {
    for (int stride = size >> 1; stride > 0; stride >>= 1) {
      int j = tid ^ stride;
      if (j > tid) {
        unsigned long long a = s[tid], c = s[j];
        bool up = ((tid & size) == 0);
        if (up ? (a < c) : (a > c)) { s[tid] = c; s[j] = a; }
      }
      __syncthreads();
    }
  }
  unsigned long long k = s[tid];
  unsigned int fbits = (unsigned int)(k >> 18);
  int idx = (IMGPIX-1) - (int)(k & 0x3FFFFull);
  int y = idx >> 9, x = idx & 511;
  float val = fbits ? __uint_as_float(fbits) : -INFINITY;
  int slot = (b << 9) + tid;
  out[12288 + slot]       = val;
  out[8192 + slot*2 + 0]  = (float)x;
  out[8192 + slot*2 + 1]  = (float)y;
  out[14336 + slot]       = (val > NMS_THR) ? 1.0f : 0.0f;
  props[slot*2 + 0] = x;
  props[slot*2 + 1] = y;
}

// ---------------------------------------------------------------------------
// Stage 3+4 (MFMA 32x32x16): 2 proposals/block, 512 thr = 8 waves.
// Wave w: mg=w&3 owns oc Mtiles {2mg,2mg+1} (64 oc), ng=w>>2 = proposal.
// acc[2 Mt][2 Nt], Nt = px halves {0..31, 32..63} of proposal ng.
// X layout [row][ic], row = prop*49 + px (only px<49 stored), zero row 98.
// A operand: lane m = lane&31 = oc_in_tile, k = (lane>>5)*8 + j.
// C/D: col(n) = lane&31, row(m) = (reg&3) + 8*(reg>>2) + 4*(lane>>5).
// ---------------------------------------------------------------------------
#define SA2 264
#define SA1 72

template<int KS, int SA>
__device__ __forceinline__ void conv32(
    const half_t* __restrict__ Wl, const half_t* __restrict__ Xin,
    int prop, int mtb, int l31, int lh, f32x16 acc[2][2])
{
#pragma unroll
  for (int mt = 0; mt < 2; ++mt)
#pragma unroll
    for (int nt = 0; nt < 2; ++nt)
#pragma unroll
      for (int r = 0; r < 16; ++r) acc[mt][nt][r] = 0.f;

  for (int tap = 0; tap < 9; ++tap) {
    const int dy = tap/3 - 1, dx = tap%3 - 1;
    int xb[2];
#pragma unroll
    for (int nt = 0; nt < 2; ++nt) {
      int px = nt*32 + l31;
      int y = px/7, x = px - y*7;
      int yy = y + dy, xx = x + dx;
      bool valid = (px < 49) & (yy >= 0) & (yy < 7) & (xx >= 0) & (xx < 7);
      int row = valid ? (prop*49 + yy*7 + xx) : 98;
      xb[nt] = row*SA + lh*8;
    }
    const half_t* wb = Wl + ((size_t)(tap*KS)*256 + mtb + l31)*16 + lh*8;
#pragma unroll 4
    for (int ks = 0; ks < KS; ++ks) {
      half8 b0 = *(const half8*)(Xin + xb[0] + ks*16);
      half8 b1 = *(const half8*)(Xin + xb[1] + ks*16);
      half8 a0 = *(const half8*)(wb + (ks*256      )*16);
      half8 a1 = *(const half8*)(wb + (ks*256 + 32 )*16);
      acc[0][0] = __builtin_amdgcn_mfma_f32_32x32x16_f16(a0, b0, acc[0][0], 0,0,0);
      acc[0][1] = __builtin_amdgcn_mfma_f32_32x32x16_f16(a0, b1, acc[0][1], 0,0,0);
      acc[1][0] = __builtin_amdgcn_mfma_f32_32x32x16_f16(a1, b0, acc[1][0], 0,0,0);
      acc[1][1] = __builtin_amdgcn_mfma_f32_32x32x16_f16(a1, b1, acc[1][1], 0,0,0);
    }
  }
}

__device__ __forceinline__ void store32(
    half_t* __restrict__ X2, const float* __restrict__ bias,
    int prop, int mtb, int ntb, int l31, int lh, const f32x16& a)
{
  int px = ntb + l31;
  if (px >= 49) return;
  half_t* dst = X2 + (prop*49 + px)*SA2;
  int oc0 = mtb + 4*lh;
#pragma unroll
  for (int q = 0; q < 4; ++q) {
    int oc = oc0 + 8*q;
    half4 h;
#pragma unroll
    for (int r = 0; r < 4; ++r) {
      float v = a[4*q + r] + bias[oc + r];
      h[r] = (half_t)LRELU_F(v);
    }
    *(half4*)(dst + oc) = h;
  }
}

__global__ __launch_bounds__(512, 4) void head_k(
    const float* __restrict__ fup, const int* __restrict__ props,
    const half_t* __restrict__ W1, const half_t* __restrict__ W2,
    const half_t* __restrict__ W3,
    const float* __restrict__ qb1, const float* __restrict__ qb2,
    const float* __restrict__ qb3,
    const float* __restrict__ qfcw, const float* __restrict__ qfcb,
    float* __restrict__ out)
{
  __shared__ __align__(16) half_t X2[99*SA2];   // 52272 B; rows 0..97, zero row 98
  __shared__ __align__(16) char  U[99*SA1*2];   // X1 (14256 B) / S epilogue
  half_t* X1 = (half_t*)U;
  float*  S  = (float*)U;                        // [2 prop][256 oc]

  const int p0 = blockIdx.x*2;
  const int b  = p0 >> 9;
  const int tid = threadIdx.x;
  const int w = tid >> 6, lane = tid & 63;
  const int l31 = lane & 31, lh = lane >> 5;
  const int mg = w & 3, ng = w >> 2;        // ng = proposal
  const int mtb = mg*64;

  for (int i = tid; i < SA2; i += 512) X2[98*SA2 + i] = (half_t)0.f;
  for (int i = tid; i < SA1; i += 512) X1[98*SA1 + i] = (half_t)0.f;

  // ROI-align for both proposals (exact reference arithmetic)
  const float step = (float)(10.0/7.0);
  for (int it = tid; it < 2*CUP*49; it += 512) {
    int pp = it / (CUP*49), rem2 = it - pp*(CUP*49);
    int c = rem2 / 49, bin = rem2 - c*49;
    int iy = bin / 7, ix = bin - iy*7;
    int cx = props[2*(p0+pp)], cy = props[2*(p0+pp)+1];
    float fy = ((float)cy - 5.0f) + ((float)iy + 0.5f)*step;
    float fx = ((float)cx - 5.0f) + ((float)ix + 0.5f)*step;
    float y0f = floorf(fy), x0f = floorf(fx);
    float wy = fy - y0f,    wx = fx - x0f;
    int y0 = (int)y0f, x0 = (int)x0f;
    int y0i = min(max(y0,   0), 511), y1i = min(max(y0+1, 0), 511);
    int x0i = min(max(x0,   0), 511), x1i = min(max(x0+1, 0), 511);
    const float* f = fup + ((size_t)(b*CUP + c) << 18);
    float v00 = f[(y0i<<9)+x0i], v01 = f[(y0i<<9)+x1i];
    float v10 = f[(y1i<<9)+x0i], v11 = f[(y1i<<9)+x1i];
    float v = v00*(1.f-wy)*(1.f-wx) + v01*(1.f-wy)*wx
            + v10*wy*(1.f-wx)       + v11*wy*wx;
    X1[(pp*49 + iy*7 + ix)*SA1 + c] = (half_t)v;
  }
  __syncthreads();

  f32x16 acc[2][2];

  // conv1: ic=64, KS=4 (X1 -> X2, disjoint: no barrier before store)
  conv32<4, SA1>(W1, X1, ng, mtb, l31, lh, acc);
#pragma unroll
  for (int mt = 0; mt < 2; ++mt)
#pragma unroll
    for (int nt = 0; nt < 2; ++nt)
      store32(X2, qb1, ng, mtb + mt*32, nt*32, l31, lh, acc[mt][nt]);
  __syncthreads();

  // conv2: ic=256, KS=16, in-place
  conv32<16, SA2>(W2, X2, ng, mtb, l31, lh, acc);
  __syncthreads();
#pragma unroll
  for (int mt = 0; mt < 2; ++mt)
#pragma unroll
    for (int nt = 0; nt < 2; ++nt)
      store32(X2, qb2, ng, mtb + mt*32, nt*32, l31, lh, acc[mt][nt]);
  __syncthreads();

  // conv3 + bias + leaky + spatial max over px
  conv32<16, SA2>(W3, X2, ng, mtb, l31, lh, acc);
#pragma unroll
  for (int mt = 0; mt < 2; ++mt) {
#pragma unroll
    for (int q = 0; q < 4; ++q) {
#pragma unroll
      for (int r = 0; r < 4; ++r) {
        int oc = mtb + mt*32 + 8*q + 4*lh + r;
        float bv = qb3[oc];
        float m = LRELU_F(acc[mt][0][4*q + r] + bv);          // px = l31 < 49
        if (l31 < 17) {
          float v2 = LRELU_F(acc[mt][1][4*q + r] + bv);       // px = 32 + l31
          m = fmaxf(m, v2);
        }
#pragma unroll
        for (int d = 1; d < 32; d <<= 1) m = fmaxf(m, __shfl_xor(m, d));
        if (l31 == 0) S[ng*256 + oc] = m;
      }
    }
  }
  __syncthreads();

  // FC 256 -> 4 per proposal (P reuses X2; conv3 LDS reads drained above)
  float* P = (float*)X2;   // [8][256]  (prop*4 + j)
  {
    int pj = tid >> 8, oc = tid & 255;
    float h = S[pj*256 + oc];
#pragma unroll
    for (int j = 0; j < 4; ++j) P[(pj*4 + j)*256 + oc] = h * qfcw[j*256 + oc];
  }
  __syncthreads();
  {
    int sseg = tid >> 6, o = tid & 63;
    float v = P[sseg*256 + o] + P[sseg*256 + o + 64]
            + P[sseg*256 + o + 128] + P[sseg*256 + o + 192];
#pragma unroll
    for (int d = 1; d < 64; d <<= 1) v += __shfl_xor(v, d);
    if (o == 0) {
      int pg = p0 + (sseg >> 2), j = sseg & 3;
      out[pg*4 + j] = v + qfcb[j];
    }
  }
}

// ---------------------------------------------------------------------------
extern "C" void kernel_launch(void* const* d_in, const int* in_sizes, int n_in,
                              void* d_out, int out_size, void* d_ws, size_t ws_size,
                              hipStream_t stream)
{
  (void)in_sizes; (void)n_in; (void)out_size; (void)ws_size;
  const float* xhat  = (const float*)d_in[0];
  const float* fdown = (const float*)d_in[1];
  const float* fup   = (const float*)d_in[2];
  const float* pw1   = (const float*)d_in[3];
  const float* pb1   = (const float*)d_in[4];
  const float* pw2   = (const float*)d_in[5];
  const float* pb2   = (const float*)d_in[6];
  const float* pw3   = (const float*)d_in[7];
  const float* pb3   = (const float*)d_in[8];
  const float* pfcw  = (const float*)d_in[9];
  const float* pfcb  = (const float*)d_in[10];
  const float* qw1   = (const float*)d_in[11];
  const float* qb1   = (const float*)d_in[12];
  const float* qw2   = (const float*)d_in[13];
  const float* qb2   = (const float*)d_in[14];
  const float* qw3   = (const float*)d_in[15];
  const float* qb3   = (const float*)d_in[16];
  const float* qfcw  = (const float*)d_in[17];
  const float* qfcb  = (const float*)d_in[18];

  char* ws = (char*)d_ws;
  double*             s32   = (double*)(ws + OFF_S32);
  double*             sum   = (double*)(ws + OFF_SUM);
  unsigned long long* cnt   = (unsigned long long*)(ws + OFF_CNT);
  unsigned int*       ccnt  = (unsigned int*)(ws + OFF_CCNT);
  unsigned int*       hist  = (unsigned int*)(ws + OFF_HIST);
  unsigned long long* pfx   = (unsigned long long*)(ws + OFF_PFX);
  unsigned int*       Rbuf  = (unsigned int*)(ws + OFF_R);
  unsigned long long* bmap  = (unsigned long long*)(ws + OFF_BITMAP);
  unsigned long long* keys  = (unsigned long long*)(ws + OFF_KEYS);
  unsigned long long* sel   = (unsigned long long*)(ws + OFF_SEL);
  int*                props = (int*)(ws + OFF_PROPS);
  half_t*             Wp1   = (half_t*)(ws + OFF_W1);
  half_t*             Wp2   = (half_t*)(ws + OFF_W2);
  half_t*             Wp3   = (half_t*)(ws + OFF_W3);
  float*              out   = (float*)d_out;

  hipMemsetAsync(ws + ZERO_BASE, 0, ZERO_LEN, stream);

  const int repack_blocks = (256*64*9 + 2*256*256*9 + 255)/256;   // 5184
  repatch_k<<<512 + repack_blocks, 256, 0, stream>>>(
      fdown, pw1,pb1, pw2,pb2, pw3,pb3, pfcw,pfcb, s32,
      qw1, qw2, qw3, Wp1, Wp2, Wp3);

  mean_k   <<<4096, 256, 0, stream>>>(xhat, s32, sum, cnt, bmap);
  keyfuse_k<<<256, 512, 0, stream>>>(xhat, bmap, sum, cnt, keys, hist + 0*4*4096);
  scan_k   <<<BB, 512, 0, stream>>>(hist + 0*4*4096, pfx, Rbuf, 0);
  hist_k   <<<2048, 512, 0, stream>>>(keys, pfx, hist + 1*4*4096, 24);
  scan_k   <<<BB, 512, 0, stream>>>(hist + 1*4*4096, pfx, Rbuf, 1);
  hist_k   <<<2048, 512, 0, stream>>>(keys, pfx, hist + 2*4*4096, 12);
  scan_k   <<<BB, 512, 0, stream>>>(hist + 2*4*4096, pfx, Rbuf, 2);
  hist_k   <<<2048, 512, 0, stream>>>(keys, pfx, hist + 3*4*4096, 0);
  scan_k   <<<BB, 512, 0, stream>>>(hist + 3*4*4096, pfx, Rbuf, 3);
  collect_k<<<2048, 512, 0, stream>>>(keys, pfx, ccnt, sel);
  sortout_k<<<BB, 512, 0, stream>>>(sel, out, props);

  head_k   <<<NPROP/2, 512, 0, stream>>>(fup, props, Wp1, Wp2, Wp3,
                                         qb1, qb2, qb3, qfcw, qfcb, out);
}